// Round 19
// baseline (178.592 us; speedup 1.0000x reference)
//
#include <hip/hip_runtime.h>
#include <hip/hip_bf16.h>

// Problem constants
#define B_N   4
#define CIN_  256
#define HH_   56
#define WW_   56
#define COUT_ 256
#define KK_   9
#define HW_   3136              // 56*56
#define KDIM  2304              // CIN_*KK_  (k index = kk*256 + ci)
#define NOFF  (B_N*18*HW_)      // 225792
#define NOUT  (B_N*COUT_*HW_)   // 3211264

typedef __attribute__((ext_vector_type(8))) short short8;   // 8 bf16 (4 VGPRs)
typedef __attribute__((ext_vector_type(4))) float float4v;  // MFMA accum

__device__ __forceinline__ short f2bf_bits(float v) {
    union { __hip_bfloat16 h; short s; } u;
    u.h = __float2bfloat16(v);
    return u.s;
}
__device__ __forceinline__ float bfbits2f(short s) {
    union { unsigned u; float f; } u2;
    u2.u = ((unsigned)(unsigned short)s) << 16;
    return u2.f;
}

// ---------------------------------------------------------------------------
// k_front: ALL front-end work in one kernel.
//   bx [0,2304):      At[cout][k=kk*256+ci] bf16
//   bx [2304,3088):   xTb[b][pos][ci] bf16 (transposed x)
//   bx [3088,3536):   3x3 offset conv -> pOff[cg] partials. r19: each block
//                     now serves a 4-h QUAD, amortizing the staged-weight LDS
//                     broadcasts x4 (r18 model: 36 b128 + 18 b32 weight reads
//                     per ci per wave ~ 4.3K cyc/wave ~ 50us total = measured
//                     48us -> offset role was LDS-broadcast-bound). Per-output
//                     accumulation order is bit-identical to r18. red[] is a
//                     SEPARATE region now (weights stay live across h loop).
//                     DETERMINISTIC (no atomics: fp32 atomic jitter feeds
//                     floorf and flips bilinear corners across replays).
//                     ci loop MUST NOT unroll (r6: 256 VGPR -> 1.9GB spill).
// ---------------------------------------------------------------------------
#define NB_AT  2304
#define NB_XT  784
#define NB_OFF 448
__global__ __launch_bounds__(256) void k_front(const float* __restrict__ x,
                                               const float* __restrict__ wgt,
                                               const float* __restrict__ ow,
                                               short* __restrict__ At,
                                               short* __restrict__ xTb,
                                               float* __restrict__ pOff) {
    __shared__ float smem[6912 + 4608];          // 46 KB: weights | red
    int bx = blockIdx.x;
    int t = threadIdx.x;
    if (bx < NB_AT) {
        int i = bx*256 + t;                      // exactly COUT_*KDIM threads
        int o = i / KDIM; int r = i % KDIM;
        int kk = r >> 8;  int ci = r & 255;
        At[i] = f2bf_bits(wgt[(size_t)(o*CIN_ + ci)*9 + kk]);
        return;
    }
    if (bx < NB_AT + NB_XT) {
        float (*tile)[65] = (float(*)[65])smem;  // 16.6 KB of smem
        int g = bx - NB_AT;                      // 0..783
        int b = g / 196; int r = g % 196;
        int c0 = (r / 49) * 64; int p0 = (r % 49) * 64;
        int tp = t & 63;  int tc = t >> 6;
        #pragma unroll
        for (int i = 0; i < 16; ++i) {
            int ci = tc*16 + i;
            tile[ci][tp] = x[((size_t)b*CIN_ + c0 + ci)*HW_ + p0 + tp];
        }
        __syncthreads();
        #pragma unroll
        for (int i = 0; i < 16; ++i) {
            int p = tc*16 + i;
            xTb[((size_t)b*HW_ + p0 + p)*CIN_ + c0 + tp] = f2bf_bits(tile[tp][p]);
        }
        return;
    }
    // ---- offset-conv role: block = (b, h-quad, cg) ----
    int g = bx - NB_AT - NB_XT;                  // 0..447
    int cg = g & 7;                              // ci group 0..7
    int t2 = g >> 3;                             // 0..55
    int b = t2 / 14, hq = (t2 % 14) * 4;         // h base (4 rows per block)
    int w = t & 63;  int q = t >> 6;
    const float* xb = x + (size_t)b*CIN_*HW_;

    // stage weights raw ow -> smem[cil*216 + c*12 + kk] (16B-aligned c-rows)
    for (int i = t; i < 32*216; i += 256) {
        int cil = i / 216; int r = i % 216;
        int c = r / 12;    int kk = r % 12;
        smem[i] = (kk < 9) ? ow[((size_t)(c*CIN_) + cg*32 + cil)*9 + kk] : 0.f;
    }
    __syncthreads();

    float* red = smem + 6912;                    // separate 18 KB region
    float* pbase = pOff + (size_t)cg*NOFF;

    #pragma unroll 1
    for (int hh = 0; hh < 4; ++hh) {
        int h = hq + hh;
        float acc[18];
        #pragma unroll
        for (int c = 0; c < 18; ++c) acc[c] = 0.f;

        int y0 = h - 1, y2 = h + 1;
        bool m0 = (w < WW_) && (y0 >= 0);
        bool m1 = (w < WW_);
        bool m2 = (w < WW_) && (y2 < HH_);

        const float* xp0 = xb + (size_t)(cg*32 + q*8)*HW_;
        float v0 = m0 ? xp0[y0*WW_ + w] : 0.f;
        float v1 = m1 ? xp0[h*WW_  + w] : 0.f;
        float v2 = m2 ? xp0[y2*WW_ + w] : 0.f;

        #pragma unroll 1
        for (int i = 0; i < 8; ++i) {
            int cil = q*8 + i;                   // wave-uniform
            float n0 = 0.f, n1 = 0.f, n2 = 0.f;
            if (i < 7) {                         // r13 pipeline: next rows early
                const float* xn = xb + (size_t)(cg*32 + cil + 1)*HW_;
                n0 = m0 ? xn[y0*WW_ + w] : 0.f;
                n1 = m1 ? xn[h*WW_  + w] : 0.f;
                n2 = m2 ? xn[y2*WW_ + w] : 0.f;
            }
            float patch[9];
            {
                float c0 = v0;
                float l = __shfl_up(c0, 1);  if (w == 0) l = 0.f;
                float r = __shfl_down(c0, 1);    // lanes >=56 hold 0 -> pad ok
                patch[0] = l; patch[1] = c0; patch[2] = r;
                c0 = v1;
                l = __shfl_up(c0, 1);  if (w == 0) l = 0.f;
                r = __shfl_down(c0, 1);
                patch[3] = l; patch[4] = c0; patch[5] = r;
                c0 = v2;
                l = __shfl_up(c0, 1);  if (w == 0) l = 0.f;
                r = __shfl_down(c0, 1);
                patch[6] = l; patch[7] = c0; patch[8] = r;
            }
            const float* wr_ = smem + cil*216;   // wave-uniform LDS broadcast
            #pragma unroll
            for (int c = 0; c < 18; ++c) {
                float4 wA = *(const float4*)(wr_ + c*12);
                float4 wB = *(const float4*)(wr_ + c*12 + 4);
                float  w8 = wr_[c*12 + 8];
                acc[c] += patch[0]*wA.x + patch[1]*wA.y + patch[2]*wA.z + patch[3]*wA.w
                        + patch[4]*wB.x + patch[5]*wB.y + patch[6]*wB.z + patch[7]*wB.w
                        + patch[8]*w8;
            }
            v0 = n0; v1 = n1; v2 = n2;
        }
        __syncthreads();                         // prev-iter red consumed
        #pragma unroll
        for (int c = 0; c < 18; ++c) red[q*1152 + c*64 + w] = acc[c];
        __syncthreads();
        for (int o = t; o < 18*WW_; o += 256) {
            int c = o / WW_, w2 = o % WW_;
            float s = red[0*1152 + c*64 + w2] + red[1*1152 + c*64 + w2]
                    + red[2*1152 + c*64 + w2] + red[3*1152 + c*64 + w2];
            pbase[(size_t)(b*18 + c)*HW_ + h*WW_ + w2] = s;
        }
    }
}

// ---------------------------------------------------------------------------
// k_gemm: the r15-proven kernel VERBATIM (46.8us measured). z=3 K-split,
// XCD-aware swizzle (FETCH 88->16MB), sA+sB swizzled LDS, register prefetch,
// packed bf16 cvt, plain pout stores. NO fences, NO atomics — r17's
// per-block __threadfence caused an L2-writeback storm (gemm 51->243us).
// ---------------------------------------------------------------------------
__global__ __launch_bounds__(256) void k_gemm(const short* __restrict__ At,
                                              const short* __restrict__ xTb,
                                              const float* __restrict__ pOff,
                                              const float* __restrict__ ob,
                                              float* __restrict__ pout) {
    __shared__ short sA[128*64];     // 16 KB, swizzled
    __shared__ short sB[64*64];      // 8 KB, swizzled
    __shared__ int4   sPI[3*64];
    __shared__ float4 sPW[3*64];
    int t = threadIdx.x;

    int idx = blockIdx.x;            // 0..1175
    int xcd = idx & 7;
    int b   = xcd & 3;
    int q   = (idx >> 3)*2 + (xcd >> 2);
    int m0   = (q & 1) * 128;
    int r2   = q >> 1;
    int posb = (r2 % 49) * 64;
    int ks   = r2 / 49;              // 0..2 : kk in [ks*3, ks*3+3)
    int kt0  = ks * 768;
    int kend = kt0 + 768;

    // ---- bilinear params (inline pOff reduce, fixed order -> bit-exact) ----
    for (int e = t; e < 3*64; e += 256) {
        int kk = ks*3 + (e >> 6); int pl = e & 63;
        int pos = posb + pl;
        int h = pos / WW_, w = pos % WW_;
        size_t oy = (size_t)(b*18 + 2*kk    )*HW_ + pos;
        size_t ox = (size_t)(b*18 + 2*kk + 1)*HW_ + pos;
        float dy = ob[2*kk], dx = ob[2*kk + 1];
        #pragma unroll
        for (int cg2 = 0; cg2 < 8; ++cg2) {
            dy += pOff[(size_t)cg2*NOFF + oy];
            dx += pOff[(size_t)cg2*NOFF + ox];
        }
        float py = (float)(h - 1 + kk/3) + dy;
        float px = (float)(w - 1 + kk%3) + dx;
        float y0f = floorf(py), x0f = floorf(px);
        int y0 = (int)y0f, x0 = (int)x0f;
        float ty = py - y0f, tx = px - x0f;
        bool vy0 = (y0   >= 0) && (y0   < HH_);
        bool vy1 = (y0+1 >= 0) && (y0+1 < HH_);
        bool vx0 = (x0   >= 0) && (x0   < WW_);
        bool vx1 = (x0+1 >= 0) && (x0+1 < WW_);
        int y0c = min(max(y0,   0), HH_-1), y1c = min(max(y0+1, 0), HH_-1);
        int x0c = min(max(x0,   0), WW_-1), x1c = min(max(x0+1, 0), WW_-1);
        sPI[e] = make_int4(y0c*WW_+x0c, y0c*WW_+x1c, y1c*WW_+x0c, y1c*WW_+x1c);
        sPW[e] = make_float4((vy0 && vx0) ? (1.f-ty)*(1.f-tx) : 0.f,
                             (vy0 && vx1) ? (1.f-ty)*tx       : 0.f,
                             (vy1 && vx0) ? ty*(1.f-tx)       : 0.f,
                             (vy1 && vx1) ? ty*tx             : 0.f);
    }
    __syncthreads();

    int arow = t >> 1,  aqc = (t & 1) * 4;    // A staging: 4 chunks (64B)
    int brow = t >> 2,  bqc = (t & 3) * 2;    // B staging: 2 chunks (32B)

    int wv = t >> 6;
    int wm = (wv >> 1) * 64;
    int wn = (wv & 1) * 32;
    int lane = t & 63;
    int lm = lane & 15;
    int qd = lane >> 4;

    float4v acc[4][2];
    #pragma unroll
    for (int i = 0; i < 4; ++i)
        #pragma unroll
        for (int j = 0; j < 2; ++j) acc[i][j] = (float4v)(0.f);

    const short* gA = At + (size_t)(m0 + arow)*KDIM + aqc*8;
    const short* xb = xTb + (size_t)b*HW_*CIN_;

    short* wA[4]; short* wB[2];
    #pragma unroll
    for (int j = 0; j < 4; ++j) {
        int qq = aqc + j;
        wA[j] = sA + (((arow >> 4)*8 + qq)*16 + ((arow + 2*qq) & 15))*8;
    }
    #pragma unroll
    for (int j = 0; j < 2; ++j) {
        int qq = bqc + j;
        wB[j] = sB + (((brow >> 4)*8 + qq)*16 + ((brow + 2*qq) & 15))*8;
    }

    short8 pa[4], cg[2][4];
    float4 bwv;
    // prologue: tiles for kt = kt0 (local kk 0)
    #pragma unroll
    for (int j = 0; j < 4; ++j) pa[j] = *(const short8*)(gA + kt0 + j*8);
    {
        int4 id = sPI[brow]; bwv = sPW[brow];
        #pragma unroll
        for (int j = 0; j < 2; ++j) {
            int ci0 = (bqc + j)*8;
            cg[j][0] = *(const short8*)(xb + (size_t)id.x*CIN_ + ci0);
            cg[j][1] = *(const short8*)(xb + (size_t)id.y*CIN_ + ci0);
            cg[j][2] = *(const short8*)(xb + (size_t)id.z*CIN_ + ci0);
            cg[j][3] = *(const short8*)(xb + (size_t)id.w*CIN_ + ci0);
        }
    }

    for (int kt = kt0; kt < kend; kt += 64) {
        // blend corners; packed bf16 cvt
        short8 pk[2];
        #pragma unroll
        for (int j = 0; j < 2; ++j) {
            float f[8];
            #pragma unroll
            for (int e = 0; e < 8; ++e)
                f[e] = bwv.x*bfbits2f(cg[j][0][e]) + bwv.y*bfbits2f(cg[j][1][e])
                     + bwv.z*bfbits2f(cg[j][2][e]) + bwv.w*bfbits2f(cg[j][3][e]);
            union { short8 s8; __hip_bfloat162 h2[4]; } pu;
            #pragma unroll
            for (int e2 = 0; e2 < 4; ++e2)
                pu.h2[e2] = __float22bfloat162_rn(make_float2(f[2*e2], f[2*e2+1]));
            pk[j] = pu.s8;
        }
        __syncthreads();                       // prev-iter LDS reads done
        #pragma unroll
        for (int j = 0; j < 4; ++j) *(short8*)wA[j] = pa[j];
        #pragma unroll
        for (int j = 0; j < 2; ++j) *(short8*)wB[j] = pk[j];
        __syncthreads();
        int kt2 = kt + 64;
        if (kt2 < kend) {                      // prefetch next tiles
            #pragma unroll
            for (int j = 0; j < 4; ++j) pa[j] = *(const short8*)(gA + kt2 + j*8);
            int kkl = (kt2 >> 8) - ks*3;       // local kk 0..2
            int4 id = sPI[kkl*64 + brow]; bwv = sPW[kkl*64 + brow];
            int cb = kt2 & 255;
            #pragma unroll
            for (int j = 0; j < 2; ++j) {
                int ci0 = cb + (bqc + j)*8;
                cg[j][0] = *(const short8*)(xb + (size_t)id.x*CIN_ + ci0);
                cg[j][1] = *(const short8*)(xb + (size_t)id.y*CIN_ + ci0);
                cg[j][2] = *(const short8*)(xb + (size_t)id.z*CIN_ + ci0);
                cg[j][3] = *(const short8*)(xb + (size_t)id.w*CIN_ + ci0);
            }
        }
        #pragma unroll
        for (int kss = 0; kss < 2; ++kss) {
            int qe = kss*4 + qd;
            int sw = (lm + 2*qe) & 15;
            short8 af[4], bf[2];
            #pragma unroll
            for (int i = 0; i < 4; ++i)
                af[i] = *(short8*)(sA + ((((wm>>4) + i)*8 + qe)*16 + sw)*8);
            #pragma unroll
            for (int j = 0; j < 2; ++j)
                bf[j] = *(short8*)(sB + ((((wn>>4) + j)*8 + qe)*16 + sw)*8);
            #pragma unroll
            for (int i = 0; i < 4; ++i)
                #pragma unroll
                for (int j = 0; j < 2; ++j)
                    acc[i][j] = __builtin_amdgcn_mfma_f32_16x16x32_bf16(
                                    af[i], bf[j], acc[i][j], 0, 0, 0);
        }
    }

    // epilogue -> per-slice partial. C/D layout col=lane&15 (n), row=qd*4+r.
    float* pbase = pout + (size_t)ks*NOUT;
    #pragma unroll
    for (int i = 0; i < 4; ++i)
        #pragma unroll
        for (int j = 0; j < 2; ++j) {
            int col = posb + wn + j*16 + lm;
            #pragma unroll
            for (int r = 0; r < 4; ++r) {
                int m = m0 + wm + i*16 + qd*4 + r;
                pbase[((size_t)b*COUT_ + m)*HW_ + col] = acc[i][j][r];
            }
        }
}

// ---------------------------------------------------------------------------
// k_oreduce: out = p0 + p1 + p2 (fixed order, bit-exact; float4 vectorized).
// ---------------------------------------------------------------------------
__global__ __launch_bounds__(256) void k_oreduce(const float* __restrict__ pout,
                                                 float* __restrict__ out) {
    int i = blockIdx.x*256 + threadIdx.x;        // float4 index, NOUT/4 total
    if (i >= NOUT/4) return;
    float4 a = ((const float4*)pout)[i];
    float4 b = ((const float4*)(pout + NOUT))[i];
    float4 c = ((const float4*)(pout + 2*(size_t)NOUT))[i];
    float4 r;
    r.x = a.x + b.x + c.x;  r.y = a.y + b.y + c.y;
    r.z = a.z + b.z + c.z;  r.w = a.w + b.w + c.w;
    ((float4*)out)[i] = r;
}

// ---------------------------------------------------------------------------
extern "C" void kernel_launch(void* const* d_in, const int* in_sizes, int n_in,
                              void* d_out, int out_size, void* d_ws, size_t ws_size,
                              hipStream_t stream) {
    const float* x   = (const float*)d_in[0];
    const float* wgt = (const float*)d_in[1];
    const float* ow  = (const float*)d_in[2];
    const float* ob  = (const float*)d_in[3];
    float* out = (float*)d_out;

    char* ws = (char*)d_ws;
    // ws layout (16B aligned): At | xTb | pOff | pout[3]  (~53.4MB)
    short* At   = (short*)ws;                        // 589824*2  =  1179648
    short* xTb  = (short*)(ws + 1179648);            // 3211264*2 =  6422528
    float* pOff = (float*)(ws + 7602176);            // 8*225792*4=  7225344
    float* pout = (float*)(ws + 14827520);           // 3*12845056= 38535168

    k_front  <<<dim3(NB_AT + NB_XT + NB_OFF), 256, 0, stream>>>(x, wgt, ow, At, xTb, pOff);
    k_gemm   <<<dim3(1176),                   256, 0, stream>>>(At, xTb, pOff, ob, pout);
    k_oreduce<<<dim3(NOUT/4/256),             256, 0, stream>>>(pout, out);
}

// Round 20
// 132.861 us; speedup vs baseline: 1.3442x; 1.3442x over previous
//
#include <hip/hip_runtime.h>
#include <hip/hip_bf16.h>

// Problem constants
#define B_N   4
#define CIN_  256
#define HH_   56
#define WW_   56
#define COUT_ 256
#define KK_   9
#define HW_   3136              // 56*56
#define KDIM  2304              // CIN_*KK_  (k index = kk*256 + ci)
#define NOFF  (B_N*18*HW_)      // 225792
#define NOUT  (B_N*COUT_*HW_)   // 3211264

typedef __attribute__((ext_vector_type(8))) short short8;   // 8 bf16 (4 VGPRs)
typedef __attribute__((ext_vector_type(4))) float float4v;  // MFMA accum

__device__ __forceinline__ short f2bf_bits(float v) {
    union { __hip_bfloat16 h; short s; } u;
    u.h = __float2bfloat16(v);
    return u.s;
}
__device__ __forceinline__ float bfbits2f(short s) {
    union { unsigned u; float f; } u2;
    u2.u = ((unsigned)(unsigned short)s) << 16;
    return u2.f;
}

// ---------------------------------------------------------------------------
// k_front: prep-only now (r20: offset conv moved to MFMA — it was 1.04 GFLOP
// at ~0.1TF effective on the VALU/LDS-broadcast path, ~48us = half the
// budget; r19's broadcast-amortization trade was occupancy-negative).
//   bx [0,2304):      At[cout][k=kk*256+ci] bf16
//   bx [2304,3088):   xTb[b][pos][ci] bf16 (transposed x)
//   bx [3088,3376):   owT3[c][kk*256+ci] bf16, c in [0,32), rows 18..31 zero
// ---------------------------------------------------------------------------
#define NB_AT  2304
#define NB_XT  784
#define NB_OW3 288
__global__ __launch_bounds__(256) void k_front(const float* __restrict__ x,
                                               const float* __restrict__ wgt,
                                               const float* __restrict__ ow,
                                               short* __restrict__ At,
                                               short* __restrict__ xTb,
                                               short* __restrict__ owT3) {
    __shared__ float tile[64][65];
    int bx = blockIdx.x;
    int t = threadIdx.x;
    if (bx < NB_AT) {
        int i = bx*256 + t;                      // exactly COUT_*KDIM threads
        int o = i / KDIM; int r = i % KDIM;
        int kk = r >> 8;  int ci = r & 255;
        At[i] = f2bf_bits(wgt[(size_t)(o*CIN_ + ci)*9 + kk]);
        return;
    }
    if (bx < NB_AT + NB_XT) {
        int g = bx - NB_AT;                      // 0..783
        int b = g / 196; int r = g % 196;
        int c0 = (r / 49) * 64; int p0 = (r % 49) * 64;
        int tp = t & 63;  int tc = t >> 6;
        #pragma unroll
        for (int i = 0; i < 16; ++i) {
            int ci = tc*16 + i;
            tile[ci][tp] = x[((size_t)b*CIN_ + c0 + ci)*HW_ + p0 + tp];
        }
        __syncthreads();
        #pragma unroll
        for (int i = 0; i < 16; ++i) {
            int p = tc*16 + i;
            xTb[((size_t)b*HW_ + p0 + p)*CIN_ + c0 + tp] = f2bf_bits(tile[tp][p]);
        }
        return;
    }
    {   // owT3 role
        int i = (bx - NB_AT - NB_XT)*256 + t;    // exactly 32*KDIM threads
        int c = i / KDIM; int r = i % KDIM;
        int kk = r >> 8;  int ci = r & 255;
        owT3[i] = (c < 18) ? f2bf_bits(ow[(size_t)(c*CIN_ + ci)*9 + kk]) : 0;
    }
}

// ---------------------------------------------------------------------------
// k_offgemm: the 3x3 offset conv as MFMA GEMM. M=32 (18 real c + pad),
// N=64 pos strip, K-split z=3 (3 kk each, K=768, 12 iters of BK=64).
// B-tile = shifted rows of xTb with zero-pad masks (fixed taps — the
// degenerate case of k_gemm's bilinear gather). Geometry/swizzle/prefetch
// copied from the PROVEN k_gemm. Deterministic (fixed in-block K order,
// plain partial stores). Grid (49, 4, 3) = 588 blocks.
// ---------------------------------------------------------------------------
__global__ __launch_bounds__(256) void k_offgemm(const short* __restrict__ owT3,
                                                 const short* __restrict__ xTb,
                                                 float* __restrict__ pOff2) {
    __shared__ short sA[32*64];      // 4 KB, swizzled
    __shared__ short sB[64*64];      // 8 KB, swizzled
    __shared__ int   sP2[3*64];      // shifted-pos index per (kk,row); -1=OOB
    int t = threadIdx.x;
    int posb = blockIdx.x * 64;
    int b    = blockIdx.y;
    int ks   = blockIdx.z;           // 0..2 : kk in [ks*3, ks*3+3)
    int kt0  = ks * 768;
    int kend = kt0 + 768;

    for (int e = t; e < 3*64; e += 256) {
        int kk = ks*3 + (e >> 6); int row = e & 63;
        int pos = posb + row;
        int h = pos / WW_, w = pos % WW_;
        int yy = h + kk/3 - 1, xx = w + kk%3 - 1;
        bool v = (yy >= 0) && (yy < HH_) && (xx >= 0) && (xx < WW_);
        sP2[e] = v ? (yy*WW_ + xx) : -1;
    }
    __syncthreads();

    int arow = t >> 3,  aq  = t & 7;          // sA staging: 1 short8 each
    int brow = t >> 2,  bqc = (t & 3) * 2;    // sB staging: 2 short8 each

    int wv = t >> 6;
    int wm = (wv >> 1) * 16;         // m-tile: 0 or 16
    int wn = (wv & 1) * 32;          // n: 0 or 32
    int lane = t & 63;
    int lm = lane & 15;
    int qd = lane >> 4;

    float4v acc[2];
    acc[0] = (float4v)(0.f); acc[1] = (float4v)(0.f);

    const short* gA = owT3 + (size_t)arow*KDIM + aq*8;
    const short* xb = xTb + (size_t)b*HW_*CIN_;

    short* wA = sA + (((arow >> 4)*8 + aq)*16 + ((arow + 2*aq) & 15))*8;
    short* wB[2];
    #pragma unroll
    for (int j = 0; j < 2; ++j) {
        int qq = bqc + j;
        wB[j] = sB + (((brow >> 4)*8 + qq)*16 + ((brow + 2*qq) & 15))*8;
    }

    short8 pa, pb[2];
    const short8 zero8 = (short8)(0);
    // prologue: tiles for kt = kt0
    pa = *(const short8*)(gA + kt0);
    {
        int p2 = sP2[brow];
        #pragma unroll
        for (int j = 0; j < 2; ++j) {
            int ci0 = (kt0 & 255) + (bqc + j)*8;
            pb[j] = (p2 >= 0) ? *(const short8*)(xb + (size_t)p2*CIN_ + ci0) : zero8;
        }
    }

    for (int kt = kt0; kt < kend; kt += 64) {
        __syncthreads();                       // prev-iter LDS reads done
        *(short8*)wA = pa;
        #pragma unroll
        for (int j = 0; j < 2; ++j) *(short8*)wB[j] = pb[j];
        __syncthreads();
        int kt2 = kt + 64;
        if (kt2 < kend) {                      // prefetch next tiles
            pa = *(const short8*)(gA + kt2);
            int kkl = (kt2 >> 8) - ks*3;       // local kk 0..2
            int p2 = sP2[kkl*64 + brow];
            int cb = kt2 & 255;
            #pragma unroll
            for (int j = 0; j < 2; ++j) {
                int ci0 = cb + (bqc + j)*8;
                pb[j] = (p2 >= 0) ? *(const short8*)(xb + (size_t)p2*CIN_ + ci0) : zero8;
            }
        }
        #pragma unroll
        for (int kss = 0; kss < 2; ++kss) {
            int qe = kss*4 + qd;
            int sw = (lm + 2*qe) & 15;
            short8 af, bf[2];
            af = *(short8*)(sA + ((((wm>>4))*8 + qe)*16 + sw)*8);
            #pragma unroll
            for (int j = 0; j < 2; ++j)
                bf[j] = *(short8*)(sB + ((((wn>>4) + j)*8 + qe)*16 + sw)*8);
            #pragma unroll
            for (int j = 0; j < 2; ++j)
                acc[j] = __builtin_amdgcn_mfma_f32_16x16x32_bf16(
                             af, bf[j], acc[j], 0, 0, 0);
        }
    }

    // epilogue: per-slice partial for c<18. C/D: col=lane&15 (n), row=qd*4+r.
    float* pbase = pOff2 + (size_t)ks*NOFF;
    #pragma unroll
    for (int j = 0; j < 2; ++j) {
        int col = posb + wn + j*16 + lm;
        #pragma unroll
        for (int r = 0; r < 4; ++r) {
            int c = wm + qd*4 + r;
            if (c < 18)
                pbase[((size_t)(b*18 + c))*HW_ + col] = acc[j][r];
        }
    }
}

// ---------------------------------------------------------------------------
// k_gemm: the r15-proven kernel (46.8us measured). z=3 K-split, XCD-aware
// swizzle (FETCH 88->16MB), sA+sB swizzled LDS, register prefetch, packed
// bf16 cvt, plain pout stores. NO fences/atomics (r17: fence storm). Param
// stage now sums ob + 3 offset-GEMM partials in FIXED order (deterministic).
// ---------------------------------------------------------------------------
__global__ __launch_bounds__(256) void k_gemm(const short* __restrict__ At,
                                              const short* __restrict__ xTb,
                                              const float* __restrict__ pOff2,
                                              const float* __restrict__ ob,
                                              float* __restrict__ pout) {
    __shared__ short sA[128*64];     // 16 KB, swizzled
    __shared__ short sB[64*64];      // 8 KB, swizzled
    __shared__ int4   sPI[3*64];
    __shared__ float4 sPW[3*64];
    int t = threadIdx.x;

    int idx = blockIdx.x;            // 0..1175
    int xcd = idx & 7;
    int b   = xcd & 3;
    int q   = (idx >> 3)*2 + (xcd >> 2);
    int m0   = (q & 1) * 128;
    int r2   = q >> 1;
    int posb = (r2 % 49) * 64;
    int ks   = r2 / 49;              // 0..2 : kk in [ks*3, ks*3+3)
    int kt0  = ks * 768;
    int kend = kt0 + 768;

    // ---- bilinear params (ob + 3 slice partials, fixed order) ----
    for (int e = t; e < 3*64; e += 256) {
        int kk = ks*3 + (e >> 6); int pl = e & 63;
        int pos = posb + pl;
        int h = pos / WW_, w = pos % WW_;
        size_t oy = (size_t)(b*18 + 2*kk    )*HW_ + pos;
        size_t ox = (size_t)(b*18 + 2*kk + 1)*HW_ + pos;
        float dy = ob[2*kk], dx = ob[2*kk + 1];
        #pragma unroll
        for (int s = 0; s < 3; ++s) {
            dy += pOff2[(size_t)s*NOFF + oy];
            dx += pOff2[(size_t)s*NOFF + ox];
        }
        float py = (float)(h - 1 + kk/3) + dy;
        float px = (float)(w - 1 + kk%3) + dx;
        float y0f = floorf(py), x0f = floorf(px);
        int y0 = (int)y0f, x0 = (int)x0f;
        float ty = py - y0f, tx = px - x0f;
        bool vy0 = (y0   >= 0) && (y0   < HH_);
        bool vy1 = (y0+1 >= 0) && (y0+1 < HH_);
        bool vx0 = (x0   >= 0) && (x0   < WW_);
        bool vx1 = (x0+1 >= 0) && (x0+1 < WW_);
        int y0c = min(max(y0,   0), HH_-1), y1c = min(max(y0+1, 0), HH_-1);
        int x0c = min(max(x0,   0), WW_-1), x1c = min(max(x0+1, 0), WW_-1);
        sPI[e] = make_int4(y0c*WW_+x0c, y0c*WW_+x1c, y1c*WW_+x0c, y1c*WW_+x1c);
        sPW[e] = make_float4((vy0 && vx0) ? (1.f-ty)*(1.f-tx) : 0.f,
                             (vy0 && vx1) ? (1.f-ty)*tx       : 0.f,
                             (vy1 && vx0) ? ty*(1.f-tx)       : 0.f,
                             (vy1 && vx1) ? ty*tx             : 0.f);
    }
    __syncthreads();

    int arow = t >> 1,  aqc = (t & 1) * 4;    // A staging: 4 chunks (64B)
    int brow = t >> 2,  bqc = (t & 3) * 2;    // B staging: 2 chunks (32B)

    int wv = t >> 6;
    int wm = (wv >> 1) * 64;
    int wn = (wv & 1) * 32;
    int lane = t & 63;
    int lm = lane & 15;
    int qd = lane >> 4;

    float4v acc[4][2];
    #pragma unroll
    for (int i = 0; i < 4; ++i)
        #pragma unroll
        for (int j = 0; j < 2; ++j) acc[i][j] = (float4v)(0.f);

    const short* gA = At + (size_t)(m0 + arow)*KDIM + aqc*8;
    const short* xb = xTb + (size_t)b*HW_*CIN_;

    short* wA[4]; short* wB[2];
    #pragma unroll
    for (int j = 0; j < 4; ++j) {
        int qq = aqc + j;
        wA[j] = sA + (((arow >> 4)*8 + qq)*16 + ((arow + 2*qq) & 15))*8;
    }
    #pragma unroll
    for (int j = 0; j < 2; ++j) {
        int qq = bqc + j;
        wB[j] = sB + (((brow >> 4)*8 + qq)*16 + ((brow + 2*qq) & 15))*8;
    }

    short8 pa[4], cg[2][4];
    float4 bwv;
    // prologue: tiles for kt = kt0 (local kk 0)
    #pragma unroll
    for (int j = 0; j < 4; ++j) pa[j] = *(const short8*)(gA + kt0 + j*8);
    {
        int4 id = sPI[brow]; bwv = sPW[brow];
        #pragma unroll
        for (int j = 0; j < 2; ++j) {
            int ci0 = (bqc + j)*8;
            cg[j][0] = *(const short8*)(xb + (size_t)id.x*CIN_ + ci0);
            cg[j][1] = *(const short8*)(xb + (size_t)id.y*CIN_ + ci0);
            cg[j][2] = *(const short8*)(xb + (size_t)id.z*CIN_ + ci0);
            cg[j][3] = *(const short8*)(xb + (size_t)id.w*CIN_ + ci0);
        }
    }

    for (int kt = kt0; kt < kend; kt += 64) {
        // blend corners; packed bf16 cvt
        short8 pk[2];
        #pragma unroll
        for (int j = 0; j < 2; ++j) {
            float f[8];
            #pragma unroll
            for (int e = 0; e < 8; ++e)
                f[e] = bwv.x*bfbits2f(cg[j][0][e]) + bwv.y*bfbits2f(cg[j][1][e])
                     + bwv.z*bfbits2f(cg[j][2][e]) + bwv.w*bfbits2f(cg[j][3][e]);
            union { short8 s8; __hip_bfloat162 h2[4]; } pu;
            #pragma unroll
            for (int e2 = 0; e2 < 4; ++e2)
                pu.h2[e2] = __float22bfloat162_rn(make_float2(f[2*e2], f[2*e2+1]));
            pk[j] = pu.s8;
        }
        __syncthreads();                       // prev-iter LDS reads done
        #pragma unroll
        for (int j = 0; j < 4; ++j) *(short8*)wA[j] = pa[j];
        #pragma unroll
        for (int j = 0; j < 2; ++j) *(short8*)wB[j] = pk[j];
        __syncthreads();
        int kt2 = kt + 64;
        if (kt2 < kend) {                      // prefetch next tiles
            #pragma unroll
            for (int j = 0; j < 4; ++j) pa[j] = *(const short8*)(gA + kt2 + j*8);
            int kkl = (kt2 >> 8) - ks*3;       // local kk 0..2
            int4 id = sPI[kkl*64 + brow]; bwv = sPW[kkl*64 + brow];
            int cb = kt2 & 255;
            #pragma unroll
            for (int j = 0; j < 2; ++j) {
                int ci0 = cb + (bqc + j)*8;
                cg[j][0] = *(const short8*)(xb + (size_t)id.x*CIN_ + ci0);
                cg[j][1] = *(const short8*)(xb + (size_t)id.y*CIN_ + ci0);
                cg[j][2] = *(const short8*)(xb + (size_t)id.z*CIN_ + ci0);
                cg[j][3] = *(const short8*)(xb + (size_t)id.w*CIN_ + ci0);
            }
        }
        #pragma unroll
        for (int kss = 0; kss < 2; ++kss) {
            int qe = kss*4 + qd;
            int sw = (lm + 2*qe) & 15;
            short8 af[4], bf[2];
            #pragma unroll
            for (int i = 0; i < 4; ++i)
                af[i] = *(short8*)(sA + ((((wm>>4) + i)*8 + qe)*16 + sw)*8);
            #pragma unroll
            for (int j = 0; j < 2; ++j)
                bf[j] = *(short8*)(sB + ((((wn>>4) + j)*8 + qe)*16 + sw)*8);
            #pragma unroll
            for (int i = 0; i < 4; ++i)
                #pragma unroll
                for (int j = 0; j < 2; ++j)
                    acc[i][j] = __builtin_amdgcn_mfma_f32_16x16x32_bf16(
                                    af[i], bf[j], acc[i][j], 0, 0, 0);
        }
    }

    // epilogue -> per-slice partial. C/D layout col=lane&15 (n), row=qd*4+r.
    float* pbase = pout + (size_t)ks*NOUT;
    #pragma unroll
    for (int i = 0; i < 4; ++i)
        #pragma unroll
        for (int j = 0; j < 2; ++j) {
            int col = posb + wn + j*16 + lm;
            #pragma unroll
            for (int r = 0; r < 4; ++r) {
                int m = m0 + wm + i*16 + qd*4 + r;
                pbase[((size_t)b*COUT_ + m)*HW_ + col] = acc[i][j][r];
            }
        }
}

// ---------------------------------------------------------------------------
// k_oreduce: out = p0 + p1 + p2 (fixed order, bit-exact; float4 vectorized).
// ---------------------------------------------------------------------------
__global__ __launch_bounds__(256) void k_oreduce(const float* __restrict__ pout,
                                                 float* __restrict__ out) {
    int i = blockIdx.x*256 + threadIdx.x;        // float4 index, NOUT/4 total
    if (i >= NOUT/4) return;
    float4 a = ((const float4*)pout)[i];
    float4 b = ((const float4*)(pout + NOUT))[i];
    float4 c = ((const float4*)(pout + 2*(size_t)NOUT))[i];
    float4 r;
    r.x = a.x + b.x + c.x;  r.y = a.y + b.y + c.y;
    r.z = a.z + b.z + c.z;  r.w = a.w + b.w + c.w;
    ((float4*)out)[i] = r;
}

// ---------------------------------------------------------------------------
extern "C" void kernel_launch(void* const* d_in, const int* in_sizes, int n_in,
                              void* d_out, int out_size, void* d_ws, size_t ws_size,
                              hipStream_t stream) {
    const float* x   = (const float*)d_in[0];
    const float* wgt = (const float*)d_in[1];
    const float* ow  = (const float*)d_in[2];
    const float* ob  = (const float*)d_in[3];
    float* out = (float*)d_out;

    char* ws = (char*)d_ws;
    // ws layout (16B aligned): At | xTb | owT3 | pOff2[3] | pout[3]  (~49MB)
    short* At    = (short*)ws;                       // 589824*2  =  1179648
    short* xTb   = (short*)(ws + 1179648);           // 3211264*2 =  6422528
    short* owT3  = (short*)(ws + 7602176);           // 32*2304*2 =   147456
    float* pOff2 = (float*)(ws + 7749632);           // 3*225792*4=  2709504
    float* pout  = (float*)(ws + 10459136);          // 3*12845056= 38535168

    k_front  <<<dim3(NB_AT + NB_XT + NB_OW3), 256, 0, stream>>>(x, wgt, ow, At, xTb, owT3);
    k_offgemm<<<dim3(49, 4, 3),               256, 0, stream>>>(owT3, xTb, pOff2);
    k_gemm   <<<dim3(1176),                   256, 0, stream>>>(At, xTb, pOff2, ob, pout);
    k_oreduce<<<dim3(NOUT/4/256),             256, 0, stream>>>(pout, out);
}